// Round 7
// baseline (1736.953 us; speedup 1.0000x reference)
//
#include <hip/hip_runtime.h>

// DSTP-RNN fused forward v5: 512-thread WG (8 waves), one batch element per WG.
// v4 finding: VGPR=124 blocks 2-WG/CU co-residency (4 waves/SIMD x 128 = full
// 512-reg file; HW won't allocate it). v5 forces VGPR <= 112 (4x112=448):
// restructured Uenc post-pass (acc[8] x 2 halves, no unroll), unroll-4 on the
// encoder attention loop, and amdgpu_num_vgpr(112) hard cap.
// LDS unchanged from v4: 80400 B -> 2 WG/CU (proven fit at 80496 in round 4).

#define TSTEPS 128

// LDS float offsets (total 20100 floats = 80400 B)
#define ENC    0        // [128][64] encoded h (lane-major)
#define UENC   8192     // [64][136] Uenc transposed (136%32=8 -> 2-way reads)
#define UE     16896    // 1024: Ue_w (encoder) ; decoder const pool overlays
#define CTLT   17920    // [8][68] conv tile transposed ; DC_YH overlays (decoder)
#define XVE    18464    // [128][2] interleaved (x_j, ve_j) / (x1_j, vd_j)
#define HSB4   18720    // 144: [h|s] (or [d|sp]) as 4 chunks of 32 @ stride 36
#define GBUF   18864    // [512] partials
#define RED    19376    // [512] enc e-partials ; GB2 (dec preacts, 256) + CTV (at +256) overlay
#define IMG    19888    // [84] 9x9 image ; TYP (head) overlays
#define LBUF   19972    // [128] l / beta ; REDS overlays (disjoint intervals)
#define SMEMF  20100    // floats -> 80400 bytes

// decoder const overlays (UE region)
#define DC_VD    (UE + 0)
#define DC_WT    (UE + 64)    // 65
#define DC_DWIH  (UE + 192)   // 256
#define DC_DBIAS (UE + 448)   // 256
#define DC_WDB   (UE + 704)   // 64
#define DC_WYB   (UE + 768)   // 64
#define DC_VY    (UE + 832)   // 64
#define DC_SC    (UE + 896)   // wtb, vyb
#define DC_YH    CTLT         // 128
#define GB2      RED          // 256 (dec preacts)
#define CTV      (RED + 256)  // 64 (dec c_t; survives loop for head)
#define TYP      IMG
#define REDS     LBUF         // scalar y_tilda (D->E write, E->F read; LBUF idle there)

// state-vector chunk addressing: element i of 128-vector -> chunk i>>5 @ stride 36
#define HS(i) (HSB4 + ((i) >> 5) * 36 + ((i) & 31))

__device__ __forceinline__ float rcpf(float x) { return __builtin_amdgcn_rcpf(x); }
__device__ __forceinline__ float fsigm(float x) { return rcpf(1.0f + __expf(-x)); }
__device__ __forceinline__ float ftanh(float x) { return 1.0f - 2.0f * rcpf(1.0f + __expf(2.0f * x)); }

#define FMA4(d_, p_, q_) \
    d_ = fmaf((p_).x, (q_).x, d_); d_ = fmaf((p_).y, (q_).y, d_); \
    d_ = fmaf((p_).z, (q_).z, d_); d_ = fmaf((p_).w, (q_).w, d_);

__global__ __attribute__((amdgpu_num_vgpr(112))) __launch_bounds__(512, 2)
void dstp_kernel(
    const float* __restrict__ Xh,   const float* __restrict__ yh,
    const float* __restrict__ convw,const float* __restrict__ convb,
    const float* __restrict__ Wew,  const float* __restrict__ Web,
    const float* __restrict__ Uew,  const float* __restrict__ vew,
    const float* __restrict__ eWih, const float* __restrict__ eWhh,
    const float* __restrict__ ebih, const float* __restrict__ ebhh,
    const float* __restrict__ Wdw,  const float* __restrict__ Wdb,
    const float* __restrict__ Udw,  const float* __restrict__ vdw,
    const float* __restrict__ wtw,  const float* __restrict__ wtb,
    const float* __restrict__ dWih, const float* __restrict__ dWhh,
    const float* __restrict__ dbih, const float* __restrict__ dbhh,
    const float* __restrict__ Wyw,  const float* __restrict__ Wyb,
    const float* __restrict__ vyw,  const float* __restrict__ vyb,
    float* __restrict__ out)
{
    extern __shared__ float sm[];
    const int tid = threadIdx.x;
    const int b   = blockIdx.x;

    // init: stage Ue_w, ve into XVE.y, zero state chunks
    for (int i = tid; i < 1024; i += 512) sm[UE + i] = Uew[i];
    if (tid < 128) sm[XVE + tid * 2 + 1] = vew[tid];
    if (tid < 144) sm[HSB4 + tid] = 0.0f;
    __syncthreads();

    // ===================== ENCODER =====================
    for (int t = 0; t < TSTEPS; ++t) {
        // img load + (c) x[j] = [h,s].We_w[j,:] + We_b[j]  (j=tid>>2, q=chunk)
        if (tid < 81) sm[IMG + tid] = Xh[((size_t)b * TSTEPS + t) * 81 + tid];
        {
            int j = tid >> 2, q = tid & 3;
            const float4* wr = reinterpret_cast<const float4*>(Wew + j * 128 + q * 32);
            const float4* hv = reinterpret_cast<const float4*>(sm + HSB4 + q * 36);
            float acc = 0.0f;
#pragma unroll
            for (int k = 0; k < 8; ++k) { float4 wv = wr[k], xv = hv[k]; FMA4(acc, wv, xv) }
            acc += __shfl_xor(acc, 1);
            acc += __shfl_xor(acc, 2);
            if (q == 0) sm[XVE + j * 2] = acc + Web[j];
        }
        __syncthreads(); // A
        // conv + relu -> CTLT[r][m]
        {
            int m = tid >> 3, r = tid & 7;
            const float* kw = convw + m * 18;
            float acc = convb[m];
#pragma unroll
            for (int w = 0; w < 9; ++w) {
                acc = fmaf(sm[IMG + r * 9 + w],     kw[w],     acc);
                acc = fmaf(sm[IMG + r * 9 + 9 + w], kw[9 + w], acc);
            }
            sm[CTLT + r * 68 + m] = fmaxf(acc, 0.0f);
        }
        __syncthreads(); // B
        const int m = tid & 63;
        float cr[8];
#pragma unroll
        for (int c = 0; c < 8; ++c) cr[c] = sm[CTLT + c * 68 + m];
        // (d) e partials: lane=m, wave w covers 16 j (Ue rows broadcast)
        {
            int w = tid >> 6;
            float eacc = 0.0f;
#pragma unroll 4
            for (int jj = 0; jj < 16; ++jj) {
                int j = w * 16 + jj;
                float4 u0 = *reinterpret_cast<const float4*>(sm + UE + j * 8);
                float4 u1 = *reinterpret_cast<const float4*>(sm + UE + j * 8 + 4);
                float2 xv = *reinterpret_cast<const float2*>(sm + XVE + j * 2);
                float s = xv.x;
                s = fmaf(u0.x, cr[0], s); s = fmaf(u0.y, cr[1], s);
                s = fmaf(u0.z, cr[2], s); s = fmaf(u0.w, cr[3], s);
                s = fmaf(u1.x, cr[4], s); s = fmaf(u1.y, cr[5], s);
                s = fmaf(u1.z, cr[6], s); s = fmaf(u1.w, cr[7], s);
                eacc = fmaf(ftanh(s), xv.y, eacc);
            }
            sm[RED + w * 64 + m] = eacc;
        }
        __syncthreads(); // C
        // (ef) per-wave redundant softmax + w_in butterfly (all lanes end with w_in)
        float win[8];
        {
            float e = 0.0f;
#pragma unroll
            for (int p = 0; p < 8; ++p) e += sm[RED + p * 64 + m];
            float mx = e;
#pragma unroll
            for (int dd = 1; dd < 64; dd <<= 1) mx = fmaxf(mx, __shfl_xor(mx, dd));
            float ex = __expf(e - mx);
            float ssum = ex;
#pragma unroll
            for (int dd = 1; dd < 64; dd <<= 1) ssum += __shfl_xor(ssum, dd);
            float al = ex * rcpf(ssum);
#pragma unroll
            for (int c = 0; c < 8; ++c) win[c] = al * cr[c];
#pragma unroll
            for (int dd = 1; dd < 64; dd <<= 1) {
#pragma unroll
                for (int c = 0; c < 8; ++c) win[c] += __shfl_xor(win[c], dd);
            }
        }
        // (g) LSTM preact row j (w_in in regs; h from chunk hk)
        {
            int j = tid >> 1, hk = tid & 1;
            const float4* whh = reinterpret_cast<const float4*>(eWhh + j * 64 + hk * 32);
            const float4* hv  = reinterpret_cast<const float4*>(sm + HSB4 + hk * 36);
            float acc = 0.0f;
#pragma unroll
            for (int k = 0; k < 8; ++k) { float4 wv = whh[k], xv = hv[k]; FMA4(acc, wv, xv) }
            acc += __shfl_xor(acc, 1);
            if (hk == 0) {
                const float4* wih = reinterpret_cast<const float4*>(eWih + j * 8);
                float4 a0 = wih[0], a1 = wih[1];
                float acc2 = ebih[j] + ebhh[j];
                acc2 = fmaf(a0.x, win[0], acc2); acc2 = fmaf(a0.y, win[1], acc2);
                acc2 = fmaf(a0.z, win[2], acc2); acc2 = fmaf(a0.w, win[3], acc2);
                acc2 = fmaf(a1.x, win[4], acc2); acc2 = fmaf(a1.y, win[5], acc2);
                acc2 = fmaf(a1.z, win[6], acc2); acc2 = fmaf(a1.w, win[7], acc2);
                sm[GBUF + j] = acc + acc2;
            }
        }
        __syncthreads(); // D
        // (h) gates -> h,s ; encoded row
        if (tid < 64) {
            float gi = sm[GBUF + tid],       gf = sm[GBUF + 64 + tid];
            float gg = sm[GBUF + 128 + tid], go = sm[GBUF + 192 + tid];
            float c = fsigm(gf) * sm[HS(64 + tid)] + fsigm(gi) * ftanh(gg);
            float h = fsigm(go) * ftanh(c);
            sm[HS(tid)] = h;
            sm[HS(64 + tid)] = c;
            sm[ENC + t * 64 + tid] = h;
        }
        __syncthreads(); // E
    }

    // ===== decoder const staging + Uenc post-pass =====
    if (tid < 64)  sm[DC_VD + tid] = vdw[tid];
    if (tid < 65)  sm[DC_WT + tid] = wtw[tid];
    if (tid < 256) { sm[DC_DWIH + tid] = dWih[tid]; sm[DC_DBIAS + tid] = dbih[tid] + dbhh[tid]; }
    if (tid < 64)  { sm[DC_WDB + tid] = Wdb[tid]; sm[DC_WYB + tid] = Wyb[tid]; sm[DC_VY + tid] = vyw[tid]; }
    if (tid < 64)  sm[XVE + tid * 2 + 1] = vdw[tid];
    if (tid < 144) sm[HSB4 + tid] = 0.0f;            // d, sp = 0
    if (tid < 128) sm[DC_YH + tid] = yh[(size_t)b * TSTEPS + tid];
    if (tid == 0)  { sm[DC_SC] = wtb[0]; sm[DC_SC + 1] = vyb[0]; }
    // Uenc[j][tt] = sum_k Ud[j][k]*ENC[tt][k]; j=lane, ENC reads broadcast.
    // Two non-unrolled halves of 8 rows each keep register pressure low
    // (this pass runs once; its cost is negligible vs the 128-step loops).
    {
        int j = tid & 63, e8 = tid >> 6;
#pragma unroll 1
        for (int half = 0; half < 2; ++half) {
            float acc[8];
#pragma unroll
            for (int i = 0; i < 8; ++i) acc[i] = 0.0f;
#pragma unroll
            for (int kc = 0; kc < 4; ++kc) {
                const float4* ud = reinterpret_cast<const float4*>(Udw + j * 64 + kc * 16);
                float4 u0 = ud[0], u1 = ud[1], u2 = ud[2], u3 = ud[3];
#pragma unroll
                for (int i = 0; i < 8; ++i) {
                    const float4* er = reinterpret_cast<const float4*>(
                        sm + ENC + (e8 * 16 + half * 8 + i) * 64 + kc * 16);
                    float4 e0 = er[0], e1 = er[1], e2 = er[2], e3 = er[3];
                    float a = acc[i];
                    FMA4(a, u0, e0) FMA4(a, u1, e1) FMA4(a, u2, e2) FMA4(a, u3, e3)
                    acc[i] = a;
                }
            }
#pragma unroll
            for (int i = 0; i < 8; ++i)
                sm[UENC + j * 136 + e8 * 16 + half * 8 + i] = acc[i];
        }
    }
    __syncthreads();

    // ===================== DECODER =====================
    for (int t = 0; t < TSTEPS; ++t) {
        // (a) x1[j] = [d,sp].Wd_w[j,:] + Wd_b[j]  (o = 16-float piece, chunked)
        {
            int j = tid >> 3, o = tid & 7;
            const float4* wd = reinterpret_cast<const float4*>(Wdw + j * 128 + o * 16);
            const float4* dv = reinterpret_cast<const float4*>(sm + HSB4 + (o >> 1) * 36 + (o & 1) * 16);
            float acc = 0.0f;
#pragma unroll
            for (int k = 0; k < 4; ++k) { float4 wv = wd[k], xv = dv[k]; FMA4(acc, wv, xv) }
            acc += __shfl_xor(acc, 1);
            acc += __shfl_xor(acc, 2);
            acc += __shfl_xor(acc, 4);
            if (o == 0) sm[XVE + j * 2] = acc + sm[DC_WDB + j];
        }
        __syncthreads(); // A
        // (b) l[tt] = sum_j tanh(x1[j] + Uenc[j][tt]) * vd[j]
        {
            int tt = tid >> 2, q = tid & 3;
            float acc = 0.0f;
#pragma unroll 4
            for (int jj = 0; jj < 16; ++jj) {
                int j = jj * 4 + q;
                float u = sm[UENC + j * 136 + tt];
                float2 xv = *reinterpret_cast<const float2*>(sm + XVE + j * 2);
                acc = fmaf(ftanh(xv.x + u), xv.y, acc);
            }
            acc += __shfl_xor(acc, 1);
            acc += __shfl_xor(acc, 2);
            if (q == 0) sm[LBUF + tt] = acc;
        }
        __syncthreads(); // B
        // (c) softmax over 128 tt (wave 0)
        if (tid < 64) {
            float v0 = sm[LBUF + tid], v1 = sm[LBUF + 64 + tid];
            float mx = fmaxf(v0, v1);
#pragma unroll
            for (int dd = 1; dd < 64; dd <<= 1) mx = fmaxf(mx, __shfl_xor(mx, dd));
            float e0 = __expf(v0 - mx), e1 = __expf(v1 - mx);
            float s = e0 + e1;
#pragma unroll
            for (int dd = 1; dd < 64; dd <<= 1) s += __shfl_xor(s, dd);
            float r = rcpf(s);
            sm[LBUF + tid] = e0 * r;
            sm[LBUF + 64 + tid] = e1 * r;
        }
        __syncthreads(); // C
        // hhdot (latency overlap) + (d) c_t partials
        float hacc = 0.0f;
        {
            int j = tid >> 1, hk = tid & 1;
            const float4* whh = reinterpret_cast<const float4*>(dWhh + j * 64 + hk * 32);
            const float4* dv  = reinterpret_cast<const float4*>(sm + HSB4 + hk * 36);
#pragma unroll
            for (int k = 0; k < 8; ++k) { float4 wv = whh[k], xv = dv[k]; FMA4(hacc, wv, xv) }
        }
        {
            int j = tid & 63, cc = tid >> 6;
            float acc = 0.0f;
#pragma unroll 4
            for (int i = 0; i < 16; ++i) {
                int ttk = cc * 16 + i;
                acc = fmaf(sm[LBUF + ttk], sm[ENC + ttk * 64 + j], acc);
            }
            sm[GBUF + cc * 64 + j] = acc;
        }
        __syncthreads(); // D
        // (e) finish c_t + y_tilda (wave 0)
        if (tid < 64) {
            float cv = 0.0f;
#pragma unroll
            for (int cc = 0; cc < 8; ++cc) cv += sm[GBUF + cc * 64 + tid];
            sm[CTV + tid] = cv;
            float p = cv * sm[DC_WT + tid];
#pragma unroll
            for (int dd = 1; dd < 64; dd <<= 1) p += __shfl_xor(p, dd);
            if (tid == 0)
                sm[REDS] = p + sm[DC_YH + t] * sm[DC_WT + 64] + sm[DC_SC];
        }
        __syncthreads(); // E
        // (f2) preact = hh + y*Wih + bias
        {
            int j = tid >> 1, hk = tid & 1;
            float acc = hacc + __shfl_xor(hacc, 1);
            if (hk == 0) {
                float yt = sm[REDS];
                sm[GB2 + j] = acc + fmaf(yt, sm[DC_DWIH + j], sm[DC_DBIAS + j]);
            }
        }
        __syncthreads(); // F
        // (g) gates -> d, sp
        if (tid < 64) {
            float gi = sm[GB2 + tid],       gf = sm[GB2 + 64 + tid];
            float gg = sm[GB2 + 128 + tid], go = sm[GB2 + 192 + tid];
            float c = fsigm(gf) * sm[HS(64 + tid)] + fsigm(gi) * ftanh(gg);
            float dnew = fsigm(go) * ftanh(c);
            sm[HS(tid)] = dnew;
            sm[HS(64 + tid)] = c;
        }
        __syncthreads(); // G
    }

    // ===================== HEAD =====================
    {
        int p = tid >> 3, o = tid & 7;
        const float4* wy = reinterpret_cast<const float4*>(Wyw + p * 128 + o * 16);
        const float4* sv = reinterpret_cast<const float4*>(
            (o < 4) ? (sm + HSB4 + (o >> 1) * 36 + (o & 1) * 16)
                    : (sm + CTV + (o - 4) * 16));
        float acc = 0.0f;
#pragma unroll
        for (int k = 0; k < 4; ++k) { float4 wv = wy[k], xv = sv[k]; FMA4(acc, wv, xv) }
        acc += __shfl_xor(acc, 1);
        acc += __shfl_xor(acc, 2);
        acc += __shfl_xor(acc, 4);
        if (o == 0) sm[TYP + p] = acc + sm[DC_WYB + p];
    }
    __syncthreads();
    if (tid < 64) {
        float v = sm[TYP + tid] * sm[DC_VY + tid];
#pragma unroll
        for (int dd = 1; dd < 64; dd <<= 1) v += __shfl_xor(v, dd);
        if (tid == 0) out[b] = v + sm[DC_SC + 1];
    }
}

extern "C" void kernel_launch(void* const* d_in, const int* in_sizes, int n_in,
                              void* d_out, int out_size, void* d_ws, size_t ws_size,
                              hipStream_t stream) {
    const float* A[26];
    for (int i = 0; i < 26; ++i) A[i] = (const float*)d_in[i];
    (void)in_sizes; (void)n_in; (void)d_ws; (void)ws_size; (void)out_size;

    (void)hipFuncSetAttribute(reinterpret_cast<const void*>(dstp_kernel),
                              hipFuncAttributeMaxDynamicSharedMemorySize,
                              SMEMF * 4);

    dstp_kernel<<<dim3(512), dim3(512), SMEMF * 4, stream>>>(
        A[0], A[1], A[2], A[3], A[4], A[5], A[6], A[7], A[8], A[9],
        A[10], A[11], A[12], A[13], A[14], A[15], A[16], A[17], A[18], A[19],
        A[20], A[21], A[22], A[23], A[24], A[25], (float*)d_out);
}

// Round 8
// 1360.539 us; speedup vs baseline: 1.2767x; 1.2767x over previous
//
#include <hip/hip_runtime.h>

// DSTP-RNN fused forward v6: TWO batch elements per 512-thread WG (one per
// 4-wave half), 256 WGs = 1 WG/CU. Rounds 5-7 proved a second 8-wave WG can
// never co-schedule at >64 VGPR (HW allocates VGPR in 64/128/256 steps), so
// instead we pack the second batch element into the same WG: same 8 waves/CU,
// 2x work per barrier interval. Per-half LDS 19652 floats; total 157216 B.

#define TSTEPS 128
#define HALF   19652   // floats per half

// per-half LDS float offsets
#define ENC    0        // [128][64] encoded h (lane-major)
#define UENC   8192     // [64][136] Uenc transposed (136%32=8 -> 2-way reads)
#define UE     16896    // 1024: Ue_w (encoder) ; decoder const pool overlays
#define CTLT   17920    // [8][68] conv tile transposed ; DC_YH overlays (decoder)
#define XVE    18464    // [128][2] interleaved (x_j, ve_j) / (x1_j, vd_j)
#define HSB4   18720    // 144: [h|s] (or [d|sp]) as 4 chunks of 32 @ stride 36
#define GBUF   18864    // 256 partials (enc preact / dec c_t partials 4x64)
#define RED    19120    // 256 enc e-partials (4x64) ; GB2 (dec preacts) overlays
#define IMG    19376    // 84: 9x9 image ; TYP (head, 64) overlays
#define LBUF   19460    // 128: l / beta ; REDS overlays (disjoint intervals)
#define CTV    19588    // 64: decoder c_t (survives loop for head)

// decoder const overlays (UE region)
#define DC_WT    (UE + 64)    // 65
#define DC_DWIH  (UE + 192)   // 256
#define DC_DBIAS (UE + 448)   // 256
#define DC_WDB   (UE + 704)   // 64
#define DC_WYB   (UE + 768)   // 64
#define DC_VY    (UE + 832)   // 64
#define DC_SC    (UE + 896)   // wtb, vyb
#define DC_YH    CTLT         // 128
#define GB2      RED          // 256 (dec preacts)
#define TYP      IMG
#define REDS     LBUF         // scalar y_tilda (D->E write, E->F read)

__device__ __forceinline__ float rcpf(float x) { return __builtin_amdgcn_rcpf(x); }
__device__ __forceinline__ float fsigm(float x) { return rcpf(1.0f + __expf(-x)); }
__device__ __forceinline__ float ftanh(float x) { return 1.0f - 2.0f * rcpf(1.0f + __expf(2.0f * x)); }

#define FMA4(d_, p_, q_) \
    d_ = fmaf((p_).x, (q_).x, d_); d_ = fmaf((p_).y, (q_).y, d_); \
    d_ = fmaf((p_).z, (q_).z, d_); d_ = fmaf((p_).w, (q_).w, d_);

__global__ __launch_bounds__(512, 1) void dstp_kernel(
    const float* __restrict__ Xh,   const float* __restrict__ yh,
    const float* __restrict__ convw,const float* __restrict__ convb,
    const float* __restrict__ Wew,  const float* __restrict__ Web,
    const float* __restrict__ Uew,  const float* __restrict__ vew,
    const float* __restrict__ eWih, const float* __restrict__ eWhh,
    const float* __restrict__ ebih, const float* __restrict__ ebhh,
    const float* __restrict__ Wdw,  const float* __restrict__ Wdb,
    const float* __restrict__ Udw,  const float* __restrict__ vdw,
    const float* __restrict__ wtw,  const float* __restrict__ wtb,
    const float* __restrict__ dWih, const float* __restrict__ dWhh,
    const float* __restrict__ dbih, const float* __restrict__ dbhh,
    const float* __restrict__ Wyw,  const float* __restrict__ Wyb,
    const float* __restrict__ vyw,  const float* __restrict__ vyb,
    float* __restrict__ out)
{
    extern __shared__ float smraw[];
    const int tid  = threadIdx.x;
    const int hb   = tid >> 8;          // half id (wave-aligned: waves 0-3 | 4-7)
    const int htid = tid & 255;         // thread id within half
    const int b    = blockIdx.x * 2 + hb;
    float* S = smraw + hb * HALF;

    // init: stage Ue_w, ve into XVE.y, zero state chunks
    for (int i = htid; i < 1024; i += 256) S[UE + i] = Uew[i];
    if (htid < 128) S[XVE + htid * 2 + 1] = vew[htid];
    if (htid < 144) S[HSB4 + htid] = 0.0f;
    __syncthreads();

    // ===================== ENCODER =====================
    for (int t = 0; t < TSTEPS; ++t) {
        // img load + (c) x[j] = [h,s].We_w[j,:] + We_b[j]  (j=htid>>1, hk=half of k)
        if (htid < 81) S[IMG + htid] = Xh[((size_t)b * TSTEPS + t) * 81 + htid];
        {
            int j = htid >> 1, hk = htid & 1;
            const float4* wr  = reinterpret_cast<const float4*>(Wew + j * 128 + hk * 64);
            const float4* hv0 = reinterpret_cast<const float4*>(S + HSB4 + (2 * hk) * 36);
            const float4* hv1 = reinterpret_cast<const float4*>(S + HSB4 + (2 * hk) * 36 + 36);
            float acc = 0.0f;
#pragma unroll
            for (int k = 0; k < 8; ++k) { float4 wv = wr[k],     xv = hv0[k]; FMA4(acc, wv, xv) }
#pragma unroll
            for (int k = 0; k < 8; ++k) { float4 wv = wr[8 + k], xv = hv1[k]; FMA4(acc, wv, xv) }
            acc += __shfl_xor(acc, 1);
            if (hk == 0) S[XVE + j * 2] = acc + Web[j];
        }
        __syncthreads(); // A
        // conv + relu -> CTLT[r][m]  (2 outputs/thread)
#pragma unroll
        for (int rep = 0; rep < 2; ++rep) {
            int idx = htid + rep * 256;
            int m = idx >> 3, r = idx & 7;
            const float* kw = convw + m * 18;
            float acc = convb[m];
#pragma unroll
            for (int w = 0; w < 9; ++w) {
                acc = fmaf(S[IMG + r * 9 + w],     kw[w],     acc);
                acc = fmaf(S[IMG + r * 9 + 9 + w], kw[9 + w], acc);
            }
            S[CTLT + r * 68 + m] = fmaxf(acc, 0.0f);
        }
        __syncthreads(); // B
        const int m = htid & 63;
        float cr[8];
#pragma unroll
        for (int c = 0; c < 8; ++c) cr[c] = S[CTLT + c * 68 + m];
        // (d) e partials: lane=m, wave w covers 32 j (Ue rows broadcast)
        {
            int w = htid >> 6;
            float eacc = 0.0f;
#pragma unroll 4
            for (int jj = 0; jj < 32; ++jj) {
                int j = w * 32 + jj;
                float4 u0 = *reinterpret_cast<const float4*>(S + UE + j * 8);
                float4 u1 = *reinterpret_cast<const float4*>(S + UE + j * 8 + 4);
                float2 xv = *reinterpret_cast<const float2*>(S + XVE + j * 2);
                float s = xv.x;
                s = fmaf(u0.x, cr[0], s); s = fmaf(u0.y, cr[1], s);
                s = fmaf(u0.z, cr[2], s); s = fmaf(u0.w, cr[3], s);
                s = fmaf(u1.x, cr[4], s); s = fmaf(u1.y, cr[5], s);
                s = fmaf(u1.z, cr[6], s); s = fmaf(u1.w, cr[7], s);
                eacc = fmaf(ftanh(s), xv.y, eacc);
            }
            S[RED + w * 64 + m] = eacc;
        }
        __syncthreads(); // C
        // (ef) per-wave redundant softmax + w_in butterfly
        float win[8];
        {
            float e = S[RED + m] + S[RED + 64 + m] + S[RED + 128 + m] + S[RED + 192 + m];
            float mx = e;
#pragma unroll
            for (int dd = 1; dd < 64; dd <<= 1) mx = fmaxf(mx, __shfl_xor(mx, dd));
            float ex = __expf(e - mx);
            float ssum = ex;
#pragma unroll
            for (int dd = 1; dd < 64; dd <<= 1) ssum += __shfl_xor(ssum, dd);
            float al = ex * rcpf(ssum);
#pragma unroll
            for (int c = 0; c < 8; ++c) win[c] = al * cr[c];
#pragma unroll
            for (int dd = 1; dd < 64; dd <<= 1) {
#pragma unroll
                for (int c = 0; c < 8; ++c) win[c] += __shfl_xor(win[c], dd);
            }
        }
        // (g) LSTM preact row j = htid (full 64-dot, w_in in regs)
        {
            int j = htid;
            const float4* wih = reinterpret_cast<const float4*>(eWih + j * 8);
            float4 a0 = wih[0], a1 = wih[1];
            float acc = ebih[j] + ebhh[j];
            acc = fmaf(a0.x, win[0], acc); acc = fmaf(a0.y, win[1], acc);
            acc = fmaf(a0.z, win[2], acc); acc = fmaf(a0.w, win[3], acc);
            acc = fmaf(a1.x, win[4], acc); acc = fmaf(a1.y, win[5], acc);
            acc = fmaf(a1.z, win[6], acc); acc = fmaf(a1.w, win[7], acc);
            const float4* whh = reinterpret_cast<const float4*>(eWhh + j * 64);
            const float4* hv0 = reinterpret_cast<const float4*>(S + HSB4);
            const float4* hv1 = reinterpret_cast<const float4*>(S + HSB4 + 36);
#pragma unroll
            for (int k = 0; k < 8; ++k) { float4 wv = whh[k],     xv = hv0[k]; FMA4(acc, wv, xv) }
#pragma unroll
            for (int k = 0; k < 8; ++k) { float4 wv = whh[8 + k], xv = hv1[k]; FMA4(acc, wv, xv) }
            S[GBUF + j] = acc;
        }
        __syncthreads(); // D
        // (h) gates -> h,s ; encoded row
        if (htid < 64) {
            float gi = S[GBUF + htid],       gf = S[GBUF + 64 + htid];
            float gg = S[GBUF + 128 + htid], go = S[GBUF + 192 + htid];
            int ck = htid >> 5, cl = htid & 31;
            float c = fsigm(gf) * S[HSB4 + (2 + ck) * 36 + cl] + fsigm(gi) * ftanh(gg);
            float h = fsigm(go) * ftanh(c);
            S[HSB4 + ck * 36 + cl] = h;
            S[HSB4 + (2 + ck) * 36 + cl] = c;
            S[ENC + t * 64 + htid] = h;
        }
        __syncthreads(); // E
    }

    // ===== decoder const staging + Uenc post-pass =====
    if (htid < 65)  S[DC_WT + htid] = wtw[htid];
    if (htid < 256) { S[DC_DWIH + htid] = dWih[htid]; S[DC_DBIAS + htid] = dbih[htid] + dbhh[htid]; }
    if (htid < 64)  { S[DC_WDB + htid] = Wdb[htid]; S[DC_WYB + htid] = Wyb[htid]; S[DC_VY + htid] = vyw[htid]; }
    if (htid < 64)  S[XVE + htid * 2 + 1] = vdw[htid];
    if (htid < 144) S[HSB4 + htid] = 0.0f;            // d, sp = 0
    if (htid < 128) S[DC_YH + htid] = yh[(size_t)b * TSTEPS + htid];
    if (htid == 0)  { S[DC_SC] = wtb[0]; S[DC_SC + 1] = vyb[0]; }
    // Uenc[j][tt] = sum_k Ud[j][k]*ENC[tt][k]; j=lane, ENC reads broadcast.
    // 4 quarters x 8 rows, non-unrolled outer -> low register pressure (runs once).
    {
        int j = htid & 63, e8 = htid >> 6;   // e8 in 0..3, covers 32 tt rows
#pragma unroll 1
        for (int q4 = 0; q4 < 4; ++q4) {
            float acc[8];
#pragma unroll
            for (int i = 0; i < 8; ++i) acc[i] = 0.0f;
#pragma unroll
            for (int kc = 0; kc < 4; ++kc) {
                const float4* ud = reinterpret_cast<const float4*>(Udw + j * 64 + kc * 16);
                float4 u0 = ud[0], u1 = ud[1], u2 = ud[2], u3 = ud[3];
#pragma unroll
                for (int i = 0; i < 8; ++i) {
                    const float4* er = reinterpret_cast<const float4*>(
                        S + ENC + (e8 * 32 + q4 * 8 + i) * 64 + kc * 16);
                    float4 e0 = er[0], e1 = er[1], e2 = er[2], e3 = er[3];
                    float a = acc[i];
                    FMA4(a, u0, e0) FMA4(a, u1, e1) FMA4(a, u2, e2) FMA4(a, u3, e3)
                    acc[i] = a;
                }
            }
#pragma unroll
            for (int i = 0; i < 8; ++i)
                S[UENC + j * 136 + e8 * 32 + q4 * 8 + i] = acc[i];
        }
    }
    __syncthreads();

    // ===================== DECODER =====================
    for (int t = 0; t < TSTEPS; ++t) {
        // (a) x1[j] = [d,sp].Wd_w[j,:] + Wd_b[j]  (j=htid>>2, o=32-float chunk)
        {
            int j = htid >> 2, o = htid & 3;
            const float4* wd = reinterpret_cast<const float4*>(Wdw + j * 128 + o * 32);
            const float4* dv = reinterpret_cast<const float4*>(S + HSB4 + o * 36);
            float acc = 0.0f;
#pragma unroll
            for (int k = 0; k < 8; ++k) { float4 wv = wd[k], xv = dv[k]; FMA4(acc, wv, xv) }
            acc += __shfl_xor(acc, 1);
            acc += __shfl_xor(acc, 2);
            if (o == 0) S[XVE + j * 2] = acc + S[DC_WDB + j];
        }
        __syncthreads(); // A
        // (b) l[tt] = sum_j tanh(x1[j] + Uenc[j][tt]) * vd[j]  (tt=htid>>1, 32 j each)
        {
            int tt = htid >> 1, hk = htid & 1;
            float acc = 0.0f;
#pragma unroll 8
            for (int jj = 0; jj < 32; ++jj) {
                int j = hk * 32 + jj;
                float u = S[UENC + j * 136 + tt];
                float2 xv = *reinterpret_cast<const float2*>(S + XVE + j * 2);
                acc = fmaf(ftanh(xv.x + u), xv.y, acc);
            }
            acc += __shfl_xor(acc, 1);
            if (hk == 0) S[LBUF + tt] = acc;
        }
        __syncthreads(); // B
        // (c) softmax over 128 tt (wave 0 of half)
        if (htid < 64) {
            float v0 = S[LBUF + htid], v1 = S[LBUF + 64 + htid];
            float mx = fmaxf(v0, v1);
#pragma unroll
            for (int dd = 1; dd < 64; dd <<= 1) mx = fmaxf(mx, __shfl_xor(mx, dd));
            float e0 = __expf(v0 - mx), e1 = __expf(v1 - mx);
            float s = e0 + e1;
#pragma unroll
            for (int dd = 1; dd < 64; dd <<= 1) s += __shfl_xor(s, dd);
            float r = rcpf(s);
            S[LBUF + htid] = e0 * r;
            S[LBUF + 64 + htid] = e1 * r;
        }
        __syncthreads(); // C
        // hhdot j=htid (full 64-dot on d) + (d) c_t partials (4 chunks x 32 tt)
        float hacc = 0.0f;
        {
            const float4* whh = reinterpret_cast<const float4*>(dWhh + htid * 64);
            const float4* dv0 = reinterpret_cast<const float4*>(S + HSB4);
            const float4* dv1 = reinterpret_cast<const float4*>(S + HSB4 + 36);
#pragma unroll
            for (int k = 0; k < 8; ++k) { float4 wv = whh[k],     xv = dv0[k]; FMA4(hacc, wv, xv) }
#pragma unroll
            for (int k = 0; k < 8; ++k) { float4 wv = whh[8 + k], xv = dv1[k]; FMA4(hacc, wv, xv) }
        }
        {
            int j = htid & 63, cc = htid >> 6;
            float acc = 0.0f;
#pragma unroll 8
            for (int i = 0; i < 32; ++i) {
                int ttk = cc * 32 + i;
                acc = fmaf(S[LBUF + ttk], S[ENC + ttk * 64 + j], acc);
            }
            S[GBUF + cc * 64 + j] = acc;
        }
        __syncthreads(); // D
        // (e) finish c_t + y_tilda (wave 0 of half)
        if (htid < 64) {
            float cv = S[GBUF + htid] + S[GBUF + 64 + htid] +
                       S[GBUF + 128 + htid] + S[GBUF + 192 + htid];
            S[CTV + htid] = cv;
            float p = cv * S[DC_WT + htid];
#pragma unroll
            for (int dd = 1; dd < 64; dd <<= 1) p += __shfl_xor(p, dd);
            if (htid == 0)
                S[REDS] = p + S[DC_YH + t] * S[DC_WT + 64] + S[DC_SC];
        }
        __syncthreads(); // E
        // (f2) preact = hh + y*Wih + bias  (j = htid)
        {
            float yt = S[REDS];
            S[GB2 + htid] = hacc + fmaf(yt, S[DC_DWIH + htid], S[DC_DBIAS + htid]);
        }
        __syncthreads(); // F
        // (g) gates -> d, sp
        if (htid < 64) {
            float gi = S[GB2 + htid],       gf = S[GB2 + 64 + htid];
            float gg = S[GB2 + 128 + htid], go = S[GB2 + 192 + htid];
            int ck = htid >> 5, cl = htid & 31;
            float c = fsigm(gf) * S[HSB4 + (2 + ck) * 36 + cl] + fsigm(gi) * ftanh(gg);
            float dnew = fsigm(go) * ftanh(c);
            S[HSB4 + ck * 36 + cl] = dnew;
            S[HSB4 + (2 + ck) * 36 + cl] = c;
        }
        __syncthreads(); // G
    }

    // ===================== HEAD =====================
    {
        int p = htid >> 2, o = htid & 3;
        const float4* wy = reinterpret_cast<const float4*>(Wyw + p * 128 + o * 32);
        const float4* sv = reinterpret_cast<const float4*>(
            (o < 2) ? (S + HSB4 + o * 36) : (S + CTV + (o - 2) * 32));
        float acc = 0.0f;
#pragma unroll
        for (int k = 0; k < 8; ++k) { float4 wv = wy[k], xv = sv[k]; FMA4(acc, wv, xv) }
        acc += __shfl_xor(acc, 1);
        acc += __shfl_xor(acc, 2);
        if (o == 0) S[TYP + p] = acc + S[DC_WYB + p];
    }
    __syncthreads();
    if (htid < 64) {
        float v = S[TYP + htid] * S[DC_VY + htid];
#pragma unroll
        for (int dd = 1; dd < 64; dd <<= 1) v += __shfl_xor(v, dd);
        if (htid == 0) out[b] = v + S[DC_SC + 1];
    }
}

extern "C" void kernel_launch(void* const* d_in, const int* in_sizes, int n_in,
                              void* d_out, int out_size, void* d_ws, size_t ws_size,
                              hipStream_t stream) {
    const float* A[26];
    for (int i = 0; i < 26; ++i) A[i] = (const float*)d_in[i];
    (void)in_sizes; (void)n_in; (void)d_ws; (void)ws_size; (void)out_size;

    const int lds_bytes = 2 * HALF * 4;   // 157216
    (void)hipFuncSetAttribute(reinterpret_cast<const void*>(dstp_kernel),
                              hipFuncAttributeMaxDynamicSharedMemorySize,
                              lds_bytes);

    dstp_kernel<<<dim3(256), dim3(512), lds_bytes, stream>>>(
        A[0], A[1], A[2], A[3], A[4], A[5], A[6], A[7], A[8], A[9],
        A[10], A[11], A[12], A[13], A[14], A[15], A[16], A[17], A[18], A[19],
        A[20], A[21], A[22], A[23], A[24], A[25], (float*)d_out);
}